// Round 1
// baseline (943.793 us; speedup 1.0000x reference)
//
#include <hip/hip_runtime.h>
#include <math.h>

// Shapes (fixed by the problem)
#define B_   4
#define N_   16384
#define M_   4096
#define C1_  128
#define C2_  256
#define H_   256
#define K1_  384   // C1 + C2

// ---------------------------------------------------------------------------
// 1) transpose known_feats [B, C2, M] -> kfT [B, M, C2] (coalesced gathers later)
// ---------------------------------------------------------------------------
__global__ __launch_bounds__(256) void k_transpose(const float* __restrict__ kf,
                                                   float* __restrict__ kfT) {
  __shared__ float tile[32][33];
  int b  = blockIdx.z;
  int i0 = blockIdx.x * 32;   // m index
  int c0 = blockIdx.y * 32;   // channel index
  int tx  = threadIdx.x & 31;
  int tyv = threadIdx.x >> 5;     // 0..7
  const float* src = kf + ((size_t)b * C2_ + c0) * M_ + i0;
  #pragma unroll
  for (int r = 0; r < 32; r += 8)
    tile[tyv + r][tx] = src[(size_t)(tyv + r) * M_ + tx];
  __syncthreads();
  float* dst = kfT + ((size_t)b * M_ + i0) * C2_ + c0;
  #pragma unroll
  for (int r = 0; r < 32; r += 8)
    dst[(size_t)(tyv + r) * C2_ + tx] = tile[tx][tyv + r];
}

// ---------------------------------------------------------------------------
// 2) three_nn: for each unknown point, 3 smallest squared distances among M known
//    d2 computed EXACTLY like the reference: (|u|^2 + |k|^2) - 2*dot
//    strict < keeps the lower index on ties (matches jax.lax.top_k stability)
// ---------------------------------------------------------------------------
__global__ __launch_bounds__(256) void k_three_nn(const float* __restrict__ unknown,
                                                  const float* __restrict__ known,
                                                  int* __restrict__ idx_o,
                                                  float* __restrict__ w_o) {
  __shared__ float4 sk[M_];   // 64 KB: x, y, z, |k|^2
  int b = blockIdx.y;
  const float* kb = known + (size_t)b * M_ * 3;
  for (int i = threadIdx.x; i < M_; i += 256) {
    float x = kb[3*i+0], y = kb[3*i+1], z = kb[3*i+2];
    sk[i] = make_float4(x, y, z, x*x + y*y + z*z);
  }
  __syncthreads();

  int j = blockIdx.x * 256 + threadIdx.x;
  const float* up = unknown + ((size_t)b * N_ + j) * 3;
  float ux = up[0], uy = up[1], uz = up[2];
  float u2 = ux*ux + uy*uy + uz*uz;

  float d1 = 1e30f, d2 = 1e30f, d3 = 1e30f;
  int   i1 = 0,     i2 = 0,     i3 = 0;
  for (int i = 0; i < M_; ++i) {
    float4 k = sk[i];
    float dt = ux*k.x + uy*k.y + uz*k.z;
    float d  = (u2 + k.w) - 2.0f*dt;
    if (d < d3) {
      if (d < d2) {
        d3 = d2; i3 = i2;
        if (d < d1) { d2 = d1; i2 = i1; d1 = d; i1 = i; }
        else        { d2 = d;  i2 = i; }
      } else { d3 = d; i3 = i; }
    }
  }
  float r1 = 1.0f / (d1 + 1e-8f);
  float r2 = 1.0f / (d2 + 1e-8f);
  float r3 = 1.0f / (d3 + 1e-8f);
  float s  = r1 + r2 + r3;
  size_t o = ((size_t)b * N_ + j) * 3;
  idx_o[o+0] = i1; idx_o[o+1] = i2; idx_o[o+2] = i3;
  w_o[o+0] = r1 / s; w_o[o+1] = r2 / s; w_o[o+2] = r3 / s;
}

// ---------------------------------------------------------------------------
// 3) three_interpolate: out[b][c][j] = sum_k w_k * kfT[b][idx_k][c]
//    32 points per block; LDS transpose so both gather reads and global writes
//    are coalesced. Writes into d_out (reused as GEMM1 input rows 0..255).
// ---------------------------------------------------------------------------
#define IP_ 32
__global__ __launch_bounds__(256) void k_interp(const float* __restrict__ kfT,
                                                const int* __restrict__ idx,
                                                const float* __restrict__ wgt,
                                                float* __restrict__ out) {
  __shared__ float T[256 * (IP_ + 1)];   // [c][p], pad -> conflict-free
  int b  = blockIdx.y;
  int j0 = blockIdx.x * IP_;
  const float* kb = kfT + (size_t)b * M_ * C2_;
  int c = threadIdx.x;
  for (int p = 0; p < IP_; ++p) {
    size_t pj = ((size_t)b * N_ + j0 + p) * 3;   // uniform -> scalar loads
    int   i0 = idx[pj+0], i1 = idx[pj+1], i2 = idx[pj+2];
    float w0 = wgt[pj+0], w1 = wgt[pj+1], w2 = wgt[pj+2];
    T[c * (IP_ + 1) + p] = w0 * kb[(size_t)i0 * C2_ + c]
                         + w1 * kb[(size_t)i1 * C2_ + c]
                         + w2 * kb[(size_t)i2 * C2_ + c];
  }
  __syncthreads();
  for (int e = threadIdx.x; e < 256 * IP_; e += 256) {
    int cc = e >> 5, p = e & (IP_ - 1);
    out[((size_t)b * C2_ + cc) * N_ + j0 + p] = T[cc * (IP_ + 1) + p];
  }
}

// ---------------------------------------------------------------------------
// 4) fp32 GEMM, 64x64 tile, BK=16, 4x4 per thread, fused BN-stat atomics.
//    MODE 0: layer1  C = W1 @ [interp ; unknown_feats]   (K=384, split source)
//    MODE 1: layer2  C = W2 @ relu(bn1(h_pre))           (K=256, bn on load)
// ---------------------------------------------------------------------------
template <int MODE>
__global__ __launch_bounds__(256) void k_gemm(const float* __restrict__ W,
                                              const float* __restrict__ X0,
                                              const float* __restrict__ X1,
                                              const float* __restrict__ bnp,
                                              float* __restrict__ out,
                                              float* __restrict__ stats) {
  const int K = (MODE == 0) ? K1_ : H_;
  __shared__ float As[16][68];
  __shared__ float Bs[16][68];
  int b  = blockIdx.z;
  int o0 = blockIdx.y * 64;
  int j0 = blockIdx.x * 64;
  int tid = threadIdx.x;
  int tx = tid & 15, ty = tid >> 4;
  float acc[4][4] = {};
  int la_o = tid >> 2;         // 0..63
  int la_k = (tid & 3) * 4;    // 0,4,8,12
  int lb_k = tid >> 4;         // 0..15
  int lb_j = (tid & 15) * 4;   // 0..60

  for (int kt = 0; kt < K; kt += 16) {
    float4 a4 = *(const float4*)(W + (size_t)(o0 + la_o) * K + kt + la_k);
    As[la_k+0][la_o] = a4.x; As[la_k+1][la_o] = a4.y;
    As[la_k+2][la_o] = a4.z; As[la_k+3][la_o] = a4.w;
    int kg = kt + lb_k;
    float4 b4;
    if (MODE == 0) {
      const float* bp = (kg < C2_)
          ? (X0 + ((size_t)b * C2_ + kg) * N_ + j0 + lb_j)
          : (X1 + ((size_t)b * C1_ + (kg - C2_)) * N_ + j0 + lb_j);
      b4 = *(const float4*)bp;
    } else {
      b4 = *(const float4*)(X0 + ((size_t)b * H_ + kg) * N_ + j0 + lb_j);
      float sc = bnp[kg], sh = bnp[256 + kg];
      b4.x = fmaxf(fmaf(sc, b4.x, sh), 0.0f);
      b4.y = fmaxf(fmaf(sc, b4.y, sh), 0.0f);
      b4.z = fmaxf(fmaf(sc, b4.z, sh), 0.0f);
      b4.w = fmaxf(fmaf(sc, b4.w, sh), 0.0f);
    }
    *(float4*)&Bs[lb_k][lb_j] = b4;
    __syncthreads();
    #pragma unroll
    for (int k = 0; k < 16; ++k) {
      float4 av = *(const float4*)&As[k][ty * 4];
      float4 bv = *(const float4*)&Bs[k][tx * 4];
      float a[4] = {av.x, av.y, av.z, av.w};
      float c4[4] = {bv.x, bv.y, bv.z, bv.w};
      #pragma unroll
      for (int i = 0; i < 4; ++i)
        #pragma unroll
        for (int jj = 0; jj < 4; ++jj)
          acc[i][jj] = fmaf(a[i], c4[jj], acc[i][jj]);
    }
    __syncthreads();
  }

  int ob = o0 + ty * 4;
  int jb = j0 + tx * 4;
  #pragma unroll
  for (int i = 0; i < 4; ++i) {
    float4 v = make_float4(acc[i][0], acc[i][1], acc[i][2], acc[i][3]);
    *(float4*)(out + ((size_t)b * H_ + ob + i) * N_ + jb) = v;
    float s = v.x + v.y + v.z + v.w;
    float q = v.x*v.x + v.y*v.y + v.z*v.z + v.w*v.w;
    #pragma unroll
    for (int off = 8; off >= 1; off >>= 1) {
      s += __shfl_down(s, off, 16);
      q += __shfl_down(q, off, 16);
    }
    if (tx == 0) {
      atomicAdd(&stats[ob + i], s);
      atomicAdd(&stats[H_ + ob + i], q);
    }
  }
}

// ---------------------------------------------------------------------------
// 5) fold BN stats into per-channel scale/shift
// ---------------------------------------------------------------------------
__global__ void k_finalize_bn(const float* __restrict__ stats,
                              const float* __restrict__ gamma,
                              const float* __restrict__ beta,
                              float* __restrict__ bnp) {
  int c = threadIdx.x;
  const float inv = 1.0f / (float)(B_ * N_);
  float mean = stats[c] * inv;
  float var  = stats[256 + c] * inv - mean * mean;
  float rstd = 1.0f / sqrtf(var + 1e-5f);
  float sc = gamma[c] * rstd;
  bnp[c] = sc;
  bnp[256 + c] = beta[c] - mean * sc;
}

// ---------------------------------------------------------------------------
// 6) final BN + ReLU, in place on d_out
// ---------------------------------------------------------------------------
__global__ __launch_bounds__(256) void k_bn_relu(float* __restrict__ out,
                                                 const float* __restrict__ bnp) {
  size_t e = (size_t)blockIdx.x * 256 + threadIdx.x;   // float4 index
  float4 v = ((float4*)out)[e];
  int c = (int)((e >> 12) & 255);                      // 4096 float4 per row
  float sc = bnp[c], sh = bnp[256 + c];
  v.x = fmaxf(fmaf(sc, v.x, sh), 0.0f);
  v.y = fmaxf(fmaf(sc, v.y, sh), 0.0f);
  v.z = fmaxf(fmaf(sc, v.z, sh), 0.0f);
  v.w = fmaxf(fmaf(sc, v.w, sh), 0.0f);
  ((float4*)out)[e] = v;
}

// ---------------------------------------------------------------------------
extern "C" void kernel_launch(void* const* d_in, const int* in_sizes, int n_in,
                              void* d_out, int out_size, void* d_ws, size_t ws_size,
                              hipStream_t stream) {
  const float* unknown = (const float*)d_in[0];
  const float* known   = (const float*)d_in[1];
  const float* uf      = (const float*)d_in[2];
  const float* kf      = (const float*)d_in[3];
  const float* W1      = (const float*)d_in[4];
  const float* g1      = (const float*)d_in[5];
  const float* b1      = (const float*)d_in[6];
  const float* W2      = (const float*)d_in[7];
  const float* g2      = (const float*)d_in[8];
  const float* b2      = (const float*)d_in[9];
  float* out = (float*)d_out;

  // workspace layout (~85.5 MB)
  float* ws     = (float*)d_ws;
  float* kfT    = ws;                                   // 4*4096*256   = 4194304 f
  float* h_pre  = kfT + (size_t)B_ * M_ * C2_;          // 4*256*16384  = 16777216 f
  int*   idx    = (int*)(h_pre + (size_t)B_ * H_ * N_); // 4*16384*3    = 196608 i
  float* wgt    = (float*)idx + (size_t)B_ * N_ * 3;    // 196608 f
  float* stats1 = wgt + (size_t)B_ * N_ * 3;            // 512 f
  float* stats2 = stats1 + 512;                         // 512 f
  float* bnp1   = stats2 + 512;                         // 512 f
  float* bnp2   = bnp1 + 512;                           // 512 f

  hipMemsetAsync(stats1, 0, 1024 * sizeof(float), stream);  // stats1+stats2

  k_transpose<<<dim3(M_ / 32, C2_ / 32, B_), 256, 0, stream>>>(kf, kfT);
  k_three_nn<<<dim3(N_ / 256, B_), 256, 0, stream>>>(unknown, known, idx, wgt);
  k_interp<<<dim3(N_ / IP_, B_), 256, 0, stream>>>(kfT, idx, wgt, out);
  k_gemm<0><<<dim3(N_ / 64, H_ / 64, B_), 256, 0, stream>>>(W1, out, uf, nullptr, h_pre, stats1);
  k_finalize_bn<<<1, 256, 0, stream>>>(stats1, g1, b1, bnp1);
  k_gemm<1><<<dim3(N_ / 64, H_ / 64, B_), 256, 0, stream>>>(W2, h_pre, nullptr, bnp1, out, stats2);
  k_finalize_bn<<<1, 256, 0, stream>>>(stats2, g2, b2, bnp2);
  k_bn_relu<<<(B_ * (size_t)H_ * N_ / 4) / 256, 256, 0, stream>>>(out, bnp2);
}

// Round 2
// 645.737 us; speedup vs baseline: 1.4616x; 1.4616x over previous
//
#include <hip/hip_runtime.h>
#include <math.h>

// Shapes (fixed by the problem)
#define B_   4
#define N_   16384
#define M_   4096
#define C1_  128
#define C2_  256
#define H_   256
#define K1_  384   // C1 + C2

#define NC_  8           // three_nn chunks over M
#define MC_  (M_ / NC_)  // 512 knowns per chunk

typedef unsigned long long u64;

// ---------------------------------------------------------------------------
// 1) transpose known_feats [B, C2, M] -> kfT [B, M, C2] (coalesced gathers later)
// ---------------------------------------------------------------------------
__global__ __launch_bounds__(256) void k_transpose(const float* __restrict__ kf,
                                                   float* __restrict__ kfT) {
  __shared__ float tile[32][33];
  int b  = blockIdx.z;
  int i0 = blockIdx.x * 32;   // m index
  int c0 = blockIdx.y * 32;   // channel index
  int tx  = threadIdx.x & 31;
  int tyv = threadIdx.x >> 5;     // 0..7
  const float* src = kf + ((size_t)b * C2_ + c0) * M_ + i0;
  #pragma unroll
  for (int r = 0; r < 32; r += 8)
    tile[tyv + r][tx] = src[(size_t)(tyv + r) * M_ + tx];
  __syncthreads();
  float* dst = kfT + ((size_t)b * M_ + i0) * C2_ + c0;
  #pragma unroll
  for (int r = 0; r < 32; r += 8)
    dst[(size_t)(tyv + r) * C2_ + tx] = tile[tx][tyv + r];
}

// ---------------------------------------------------------------------------
// 2a) three_nn partials: each block scans one M-chunk (512 knowns, 8 KB LDS),
//     keeps per-point top-3 as packed (d_bits<<32 | idx) doubles.
//     IEEE f64 ordering of the packed value == lexicographic (d, idx) ordering
//     for all float d (incl. negatives), never NaN (d_bits <= 0x7F800000).
//     Ties -> lower index wins, exactly matching jax.lax.top_k stability.
//     Branchless sorted-insert = 5 v_min/max_f64, no divergence.
// ---------------------------------------------------------------------------
__global__ __launch_bounds__(256) void k_three_nn_part(const float* __restrict__ unknown,
                                                       const float* __restrict__ known,
                                                       double* __restrict__ part) {
  __shared__ float4 sk[MC_];   // x, y, z, |k|^2
  int b    = blockIdx.y;
  int ch   = blockIdx.z;
  int base = ch * MC_;
  const float* kb = known + ((size_t)b * M_ + base) * 3;
  for (int i = threadIdx.x; i < MC_; i += 256) {
    float x = kb[3*i+0], y = kb[3*i+1], z = kb[3*i+2];
    sk[i] = make_float4(x, y, z, x*x + y*y + z*z);
  }
  __syncthreads();

  int j = blockIdx.x * 256 + threadIdx.x;
  const float* up = unknown + ((size_t)b * N_ + j) * 3;
  float ux = up[0], uy = up[1], uz = up[2];
  float u2 = ux*ux + uy*uy + uz*uz;

  const double INF = __builtin_inf();
  double s1 = INF, s2 = INF, s3 = INF;
  #pragma unroll 4
  for (int i = 0; i < MC_; ++i) {
    float4 k = sk[i];
    float dt = ux*k.x + uy*k.y + uz*k.z;
    float d  = (u2 + k.w) - 2.0f*dt;            // identical arithmetic to ref path
    u64 pk = ((u64)__float_as_uint(d) << 32) | (unsigned)(base + i);
    double c = __longlong_as_double((long long)pk);
    double x3 = fmin(s3, c);                    // insert into sorted {s1<=s2<=s3}
    s3 = fmax(s2, x3);
    double t  = fmin(s2, x3);
    s2 = fmax(s1, t);
    s1 = fmin(s1, t);
  }
  // layout [NC][B][3][N] -> fully coalesced stores/loads
  double* p = part + ((size_t)(ch * B_ + b) * 3) * N_ + j;
  p[0]            = s1;
  p[(size_t)N_]   = s2;
  p[2*(size_t)N_] = s3;
}

// ---------------------------------------------------------------------------
// 2b) merge NC partial top-3 lists -> final idx + inverse-distance weights
// ---------------------------------------------------------------------------
__global__ __launch_bounds__(256) void k_three_merge(const double* __restrict__ part,
                                                     int* __restrict__ idx_o,
                                                     float* __restrict__ w_o) {
  int j = blockIdx.x * 256 + threadIdx.x;
  int b = blockIdx.y;
  const double* p0 = part + ((size_t)(0 * B_ + b) * 3) * N_ + j;
  double s1 = p0[0], s2 = p0[(size_t)N_], s3 = p0[2*(size_t)N_];
  #pragma unroll
  for (int c = 1; c < NC_; ++c) {
    const double* pc = part + ((size_t)(c * B_ + b) * 3) * N_ + j;
    #pragma unroll
    for (int k = 0; k < 3; ++k) {
      double cv = pc[(size_t)k * N_];
      double x3 = fmin(s3, cv);
      s3 = fmax(s2, x3);
      double t  = fmin(s2, x3);
      s2 = fmax(s1, t);
      s1 = fmin(s1, t);
    }
  }
  u64 p1 = (u64)__double_as_longlong(s1);
  u64 p2 = (u64)__double_as_longlong(s2);
  u64 p3 = (u64)__double_as_longlong(s3);
  float d1 = __uint_as_float((unsigned)(p1 >> 32));
  float d2 = __uint_as_float((unsigned)(p2 >> 32));
  float d3 = __uint_as_float((unsigned)(p3 >> 32));
  float r1 = 1.0f / (d1 + 1e-8f);
  float r2 = 1.0f / (d2 + 1e-8f);
  float r3 = 1.0f / (d3 + 1e-8f);
  float s  = r1 + r2 + r3;
  size_t o = ((size_t)b * N_ + j) * 3;
  idx_o[o+0] = (int)(unsigned)p1;
  idx_o[o+1] = (int)(unsigned)p2;
  idx_o[o+2] = (int)(unsigned)p3;
  w_o[o+0] = r1 / s; w_o[o+1] = r2 / s; w_o[o+2] = r3 / s;
}

// ---------------------------------------------------------------------------
// 3) three_interpolate: out[b][c][j] = sum_k w_k * kfT[b][idx_k][c]
// ---------------------------------------------------------------------------
#define IP_ 32
__global__ __launch_bounds__(256) void k_interp(const float* __restrict__ kfT,
                                                const int* __restrict__ idx,
                                                const float* __restrict__ wgt,
                                                float* __restrict__ out) {
  __shared__ float T[256 * (IP_ + 1)];   // [c][p], pad -> conflict-free
  int b  = blockIdx.y;
  int j0 = blockIdx.x * IP_;
  const float* kb = kfT + (size_t)b * M_ * C2_;
  int c = threadIdx.x;
  for (int p = 0; p < IP_; ++p) {
    size_t pj = ((size_t)b * N_ + j0 + p) * 3;   // uniform -> scalar loads
    int   i0 = idx[pj+0], i1 = idx[pj+1], i2 = idx[pj+2];
    float w0 = wgt[pj+0], w1 = wgt[pj+1], w2 = wgt[pj+2];
    T[c * (IP_ + 1) + p] = w0 * kb[(size_t)i0 * C2_ + c]
                         + w1 * kb[(size_t)i1 * C2_ + c]
                         + w2 * kb[(size_t)i2 * C2_ + c];
  }
  __syncthreads();
  for (int e = threadIdx.x; e < 256 * IP_; e += 256) {
    int cc = e >> 5, p = e & (IP_ - 1);
    out[((size_t)b * C2_ + cc) * N_ + j0 + p] = T[cc * (IP_ + 1) + p];
  }
}

// ---------------------------------------------------------------------------
// 4) fp32 GEMM, 64x64 tile, BK=16, 4x4 per thread, fused BN-stat atomics.
//    MODE 0: layer1  C = W1 @ [interp ; unknown_feats]   (K=384, split source)
//    MODE 1: layer2  C = W2 @ relu(bn1(h_pre))           (K=256, bn on load)
// ---------------------------------------------------------------------------
template <int MODE>
__global__ __launch_bounds__(256) void k_gemm(const float* __restrict__ W,
                                              const float* __restrict__ X0,
                                              const float* __restrict__ X1,
                                              const float* __restrict__ bnp,
                                              float* __restrict__ out,
                                              float* __restrict__ stats) {
  const int K = (MODE == 0) ? K1_ : H_;
  __shared__ float As[16][68];
  __shared__ float Bs[16][68];
  int b  = blockIdx.z;
  int o0 = blockIdx.y * 64;
  int j0 = blockIdx.x * 64;
  int tid = threadIdx.x;
  int tx = tid & 15, ty = tid >> 4;
  float acc[4][4] = {};
  int la_o = tid >> 2;         // 0..63
  int la_k = (tid & 3) * 4;    // 0,4,8,12
  int lb_k = tid >> 4;         // 0..15
  int lb_j = (tid & 15) * 4;   // 0..60

  for (int kt = 0; kt < K; kt += 16) {
    float4 a4 = *(const float4*)(W + (size_t)(o0 + la_o) * K + kt + la_k);
    As[la_k+0][la_o] = a4.x; As[la_k+1][la_o] = a4.y;
    As[la_k+2][la_o] = a4.z; As[la_k+3][la_o] = a4.w;
    int kg = kt + lb_k;
    float4 b4;
    if (MODE == 0) {
      const float* bp = (kg < C2_)
          ? (X0 + ((size_t)b * C2_ + kg) * N_ + j0 + lb_j)
          : (X1 + ((size_t)b * C1_ + (kg - C2_)) * N_ + j0 + lb_j);
      b4 = *(const float4*)bp;
    } else {
      b4 = *(const float4*)(X0 + ((size_t)b * H_ + kg) * N_ + j0 + lb_j);
      float sc = bnp[kg], sh = bnp[256 + kg];
      b4.x = fmaxf(fmaf(sc, b4.x, sh), 0.0f);
      b4.y = fmaxf(fmaf(sc, b4.y, sh), 0.0f);
      b4.z = fmaxf(fmaf(sc, b4.z, sh), 0.0f);
      b4.w = fmaxf(fmaf(sc, b4.w, sh), 0.0f);
    }
    *(float4*)&Bs[lb_k][lb_j] = b4;
    __syncthreads();
    #pragma unroll
    for (int k = 0; k < 16; ++k) {
      float4 av = *(const float4*)&As[k][ty * 4];
      float4 bv = *(const float4*)&Bs[k][tx * 4];
      float a[4] = {av.x, av.y, av.z, av.w};
      float c4[4] = {bv.x, bv.y, bv.z, bv.w};
      #pragma unroll
      for (int i = 0; i < 4; ++i)
        #pragma unroll
        for (int jj = 0; jj < 4; ++jj)
          acc[i][jj] = fmaf(a[i], c4[jj], acc[i][jj]);
    }
    __syncthreads();
  }

  int ob = o0 + ty * 4;
  int jb = j0 + tx * 4;
  #pragma unroll
  for (int i = 0; i < 4; ++i) {
    float4 v = make_float4(acc[i][0], acc[i][1], acc[i][2], acc[i][3]);
    *(float4*)(out + ((size_t)b * H_ + ob + i) * N_ + jb) = v;
    float s = v.x + v.y + v.z + v.w;
    float q = v.x*v.x + v.y*v.y + v.z*v.z + v.w*v.w;
    #pragma unroll
    for (int off = 8; off >= 1; off >>= 1) {
      s += __shfl_down(s, off, 16);
      q += __shfl_down(q, off, 16);
    }
    if (tx == 0) {
      atomicAdd(&stats[ob + i], s);
      atomicAdd(&stats[H_ + ob + i], q);
    }
  }
}

// ---------------------------------------------------------------------------
// 5) fold BN stats into per-channel scale/shift
// ---------------------------------------------------------------------------
__global__ void k_finalize_bn(const float* __restrict__ stats,
                              const float* __restrict__ gamma,
                              const float* __restrict__ beta,
                              float* __restrict__ bnp) {
  int c = threadIdx.x;
  const float inv = 1.0f / (float)(B_ * N_);
  float mean = stats[c] * inv;
  float var  = stats[256 + c] * inv - mean * mean;
  float rstd = 1.0f / sqrtf(var + 1e-5f);
  float sc = gamma[c] * rstd;
  bnp[c] = sc;
  bnp[256 + c] = beta[c] - mean * sc;
}

// ---------------------------------------------------------------------------
// 6) final BN + ReLU, in place on d_out
// ---------------------------------------------------------------------------
__global__ __launch_bounds__(256) void k_bn_relu(float* __restrict__ out,
                                                 const float* __restrict__ bnp) {
  size_t e = (size_t)blockIdx.x * 256 + threadIdx.x;   // float4 index
  float4 v = ((float4*)out)[e];
  int c = (int)((e >> 12) & 255);                      // 4096 float4 per row
  float sc = bnp[c], sh = bnp[256 + c];
  v.x = fmaxf(fmaf(sc, v.x, sh), 0.0f);
  v.y = fmaxf(fmaf(sc, v.y, sh), 0.0f);
  v.z = fmaxf(fmaf(sc, v.z, sh), 0.0f);
  v.w = fmaxf(fmaf(sc, v.w, sh), 0.0f);
  ((float4*)out)[e] = v;
}

// ---------------------------------------------------------------------------
extern "C" void kernel_launch(void* const* d_in, const int* in_sizes, int n_in,
                              void* d_out, int out_size, void* d_ws, size_t ws_size,
                              hipStream_t stream) {
  const float* unknown = (const float*)d_in[0];
  const float* known   = (const float*)d_in[1];
  const float* uf      = (const float*)d_in[2];
  const float* kf      = (const float*)d_in[3];
  const float* W1      = (const float*)d_in[4];
  const float* g1      = (const float*)d_in[5];
  const float* b1      = (const float*)d_in[6];
  const float* W2      = (const float*)d_in[7];
  const float* g2      = (const float*)d_in[8];
  const float* b2      = (const float*)d_in[9];
  float* out = (float*)d_out;

  // workspace layout (~85.5 MB); three_nn partials (12.6 MB) overlap h_pre,
  // which is only written by k_gemm<0> AFTER k_three_merge consumed them.
  float* ws     = (float*)d_ws;
  float* kfT    = ws;                                   // 4*4096*256   = 4194304 f
  float* h_pre  = kfT + (size_t)B_ * M_ * C2_;          // 4*256*16384  = 16777216 f
  int*   idx    = (int*)(h_pre + (size_t)B_ * H_ * N_); // 4*16384*3    = 196608 i
  float* wgt    = (float*)idx + (size_t)B_ * N_ * 3;    // 196608 f
  float* stats1 = wgt + (size_t)B_ * N_ * 3;            // 512 f
  float* stats2 = stats1 + 512;                         // 512 f
  float* bnp1   = stats2 + 512;                         // 512 f
  float* bnp2   = bnp1 + 512;                           // 512 f
  double* part  = (double*)h_pre;                       // NC*B*3*N doubles = 12.6 MB

  hipMemsetAsync(stats1, 0, 1024 * sizeof(float), stream);  // stats1+stats2

  k_transpose<<<dim3(M_ / 32, C2_ / 32, B_), 256, 0, stream>>>(kf, kfT);
  k_three_nn_part<<<dim3(N_ / 256, B_, NC_), 256, 0, stream>>>(unknown, known, part);
  k_three_merge<<<dim3(N_ / 256, B_), 256, 0, stream>>>(part, idx, wgt);
  k_interp<<<dim3(N_ / IP_, B_), 256, 0, stream>>>(kfT, idx, wgt, out);
  k_gemm<0><<<dim3(N_ / 64, H_ / 64, B_), 256, 0, stream>>>(W1, out, uf, nullptr, h_pre, stats1);
  k_finalize_bn<<<1, 256, 0, stream>>>(stats1, g1, b1, bnp1);
  k_gemm<1><<<dim3(N_ / 64, H_ / 64, B_), 256, 0, stream>>>(W2, h_pre, nullptr, bnp1, out, stats2);
  k_finalize_bn<<<1, 256, 0, stream>>>(stats2, g2, b2, bnp2);
  k_bn_relu<<<(B_ * (size_t)H_ * N_ / 4) / 256, 256, 0, stream>>>(out, bnp2);
}

// Round 3
// 552.801 us; speedup vs baseline: 1.7073x; 1.1681x over previous
//
#include <hip/hip_runtime.h>
#include <math.h>

// Shapes (fixed by the problem)
#define B_   4
#define N_   16384
#define M_   4096
#define C1_  128
#define C2_  256
#define H_   256
#define K1_  384   // C1 + C2

#define NC_  8           // three_nn chunks over M
#define MC_  (M_ / NC_)  // 512 knowns per chunk

typedef unsigned long long u64;
typedef __attribute__((ext_vector_type(8))) short bf16x8;   // 8 bf16 (4 VGPRs)
typedef __attribute__((ext_vector_type(4))) float f32x4;    // mfma acc
typedef __attribute__((address_space(1))) const unsigned int* gp_t;
typedef __attribute__((address_space(3))) unsigned int* lp_t;

__device__ __forceinline__ unsigned short f2bf(float x) {
  unsigned u = __float_as_uint(x);
  return (unsigned short)((u + 0x7FFFu + ((u >> 16) & 1u)) >> 16);  // RNE
}

// ---------------------------------------------------------------------------
// 1) transpose known_feats [B, C2, M] -> kfT [B, M, C2] fp32 (for gathers)
// ---------------------------------------------------------------------------
__global__ __launch_bounds__(256) void k_transpose(const float* __restrict__ kf,
                                                   float* __restrict__ kfT) {
  __shared__ float tile[32][33];
  int b  = blockIdx.z;
  int i0 = blockIdx.x * 32;
  int c0 = blockIdx.y * 32;
  int tx  = threadIdx.x & 31;
  int tyv = threadIdx.x >> 5;
  const float* src = kf + ((size_t)b * C2_ + c0) * M_ + i0;
  #pragma unroll
  for (int r = 0; r < 32; r += 8)
    tile[tyv + r][tx] = src[(size_t)(tyv + r) * M_ + tx];
  __syncthreads();
  float* dst = kfT + ((size_t)b * M_ + i0) * C2_ + c0;
  #pragma unroll
  for (int r = 0; r < 32; r += 8)
    dst[(size_t)(tyv + r) * C2_ + tx] = tile[tx][tyv + r];
}

// ---------------------------------------------------------------------------
// 2a) three_nn partials (packed (d_bits<<32|idx) doubles, branchless top-3)
// ---------------------------------------------------------------------------
__global__ __launch_bounds__(256) void k_three_nn_part(const float* __restrict__ unknown,
                                                       const float* __restrict__ known,
                                                       double* __restrict__ part) {
  __shared__ float4 sk[MC_];
  int b    = blockIdx.y;
  int ch   = blockIdx.z;
  int base = ch * MC_;
  const float* kb = known + ((size_t)b * M_ + base) * 3;
  for (int i = threadIdx.x; i < MC_; i += 256) {
    float x = kb[3*i+0], y = kb[3*i+1], z = kb[3*i+2];
    sk[i] = make_float4(x, y, z, x*x + y*y + z*z);
  }
  __syncthreads();

  int j = blockIdx.x * 256 + threadIdx.x;
  const float* up = unknown + ((size_t)b * N_ + j) * 3;
  float ux = up[0], uy = up[1], uz = up[2];
  float u2 = ux*ux + uy*uy + uz*uz;

  const double INF = __builtin_inf();
  double s1 = INF, s2 = INF, s3 = INF;
  #pragma unroll 4
  for (int i = 0; i < MC_; ++i) {
    float4 k = sk[i];
    float dt = ux*k.x + uy*k.y + uz*k.z;
    float d  = (u2 + k.w) - 2.0f*dt;
    u64 pk = ((u64)__float_as_uint(d) << 32) | (unsigned)(base + i);
    double c = __longlong_as_double((long long)pk);
    double x3 = fmin(s3, c);
    s3 = fmax(s2, x3);
    double t  = fmin(s2, x3);
    s2 = fmax(s1, t);
    s1 = fmin(s1, t);
  }
  double* p = part + ((size_t)(ch * B_ + b) * 3) * N_ + j;
  p[0]            = s1;
  p[(size_t)N_]   = s2;
  p[2*(size_t)N_] = s3;
}

// ---------------------------------------------------------------------------
// 2b) merge partials -> idx + inverse-distance weights
// ---------------------------------------------------------------------------
__global__ __launch_bounds__(256) void k_three_merge(const double* __restrict__ part,
                                                     int* __restrict__ idx_o,
                                                     float* __restrict__ w_o) {
  int j = blockIdx.x * 256 + threadIdx.x;
  int b = blockIdx.y;
  const double* p0 = part + ((size_t)b * 3) * N_ + j;
  double s1 = p0[0], s2 = p0[(size_t)N_], s3 = p0[2*(size_t)N_];
  #pragma unroll
  for (int c = 1; c < NC_; ++c) {
    const double* pc = part + ((size_t)(c * B_ + b) * 3) * N_ + j;
    #pragma unroll
    for (int k = 0; k < 3; ++k) {
      double cv = pc[(size_t)k * N_];
      double x3 = fmin(s3, cv);
      s3 = fmax(s2, x3);
      double t  = fmin(s2, x3);
      s2 = fmax(s1, t);
      s1 = fmin(s1, t);
    }
  }
  u64 p1 = (u64)__double_as_longlong(s1);
  u64 p2 = (u64)__double_as_longlong(s2);
  u64 p3 = (u64)__double_as_longlong(s3);
  float d1 = __uint_as_float((unsigned)(p1 >> 32));
  float d2 = __uint_as_float((unsigned)(p2 >> 32));
  float d3 = __uint_as_float((unsigned)(p3 >> 32));
  float r1 = 1.0f / (d1 + 1e-8f);
  float r2 = 1.0f / (d2 + 1e-8f);
  float r3 = 1.0f / (d3 + 1e-8f);
  float s  = r1 + r2 + r3;
  size_t o = ((size_t)b * N_ + j) * 3;
  idx_o[o+0] = (int)(unsigned)p1;
  idx_o[o+1] = (int)(unsigned)p2;
  idx_o[o+2] = (int)(unsigned)p3;
  w_o[o+0] = r1 / s; w_o[o+1] = r2 / s; w_o[o+2] = r3 / s;
}

// ---------------------------------------------------------------------------
// 3a) three_interpolate -> Xb1[b][j][0:256] bf16 (point-major GEMM operand)
// ---------------------------------------------------------------------------
#define IP_ 32
__global__ __launch_bounds__(256) void k_interp(const float* __restrict__ kfT,
                                                const int* __restrict__ idx,
                                                const float* __restrict__ wgt,
                                                unsigned short* __restrict__ Xb1) {
  int b  = blockIdx.y;
  int j0 = blockIdx.x * IP_;
  const float* kb = kfT + (size_t)b * M_ * C2_;
  int c = threadIdx.x;
  for (int p = 0; p < IP_; ++p) {
    size_t pj = ((size_t)b * N_ + j0 + p) * 3;   // uniform -> scalar loads
    int   i0 = idx[pj+0], i1 = idx[pj+1], i2 = idx[pj+2];
    float w0 = wgt[pj+0], w1 = wgt[pj+1], w2 = wgt[pj+2];
    float v = w0 * kb[(size_t)i0 * C2_ + c]
            + w1 * kb[(size_t)i1 * C2_ + c]
            + w2 * kb[(size_t)i2 * C2_ + c];
    Xb1[((size_t)b * N_ + j0 + p) * K1_ + c] = f2bf(v);
  }
}

// ---------------------------------------------------------------------------
// 3b) transpose+cast unknown_feats [B,C1,N] fp32 -> Xb1[b][j][256+c] bf16
// ---------------------------------------------------------------------------
__global__ __launch_bounds__(256) void k_uf_t(const float* __restrict__ uf,
                                              unsigned short* __restrict__ Xb1) {
  __shared__ float tile[32][33];
  int b  = blockIdx.z;
  int j0 = blockIdx.x * 32;
  int c0 = blockIdx.y * 32;
  int tx = threadIdx.x & 31, ty = threadIdx.x >> 5;
  const float* src = uf + ((size_t)b * C1_ + c0) * N_ + j0;
  #pragma unroll
  for (int r = 0; r < 32; r += 8)
    tile[ty + r][tx] = src[(size_t)(ty + r) * N_ + tx];
  __syncthreads();
  unsigned short* dst = Xb1 + ((size_t)b * N_ + j0) * K1_ + C2_ + c0;
  #pragma unroll
  for (int r = 0; r < 32; r += 8)
    dst[(size_t)(ty + r) * K1_ + tx] = f2bf(tile[tx][ty + r]);
}

// ---------------------------------------------------------------------------
// 3c) cast weights to bf16 (row-major unchanged)
// ---------------------------------------------------------------------------
__global__ void k_wcast(const float* __restrict__ W, unsigned short* __restrict__ Wb, int n) {
  int i = blockIdx.x * 256 + threadIdx.x;
  if (i < n) Wb[i] = f2bf(W[i]);
}

// ---------------------------------------------------------------------------
// 4) bf16 MFMA GEMM: C[m][n] = sum_k Wb[m][k] * Xb[b][n][k]
//    128x128 tile, BK=32, 4 waves (2x2 of 64x64), 16x mfma_16x16x32 per wave.
//    global_load_lds width-16 staging; fused per-channel sum/sumsq atomics.
//    OUTL 0: write h[b][n][m] fp32 (point-major, feeds bn_relu_cast)
//    OUTL 1: write out[b][m][n] fp32 (final layout)
// ---------------------------------------------------------------------------
template <int K, int OUTL>
__global__ __launch_bounds__(256) void k_gemm_mfma(const unsigned short* __restrict__ Wb,
                                                   const unsigned short* __restrict__ Xb,
                                                   float* __restrict__ outp,
                                                   float* __restrict__ stats) {
  __shared__ unsigned short As[128 * 32];   // [m][k] bf16, 8 KB
  __shared__ unsigned short Bs[128 * 32];   // [n][k] bf16, 8 KB
  int b  = blockIdx.z;
  int m0 = blockIdx.y * 128;
  int j0 = blockIdx.x * 128;
  int t  = threadIdx.x;
  int wid = t >> 6, lane = t & 63;
  int wr = wid >> 1, wc = wid & 1;          // wave quadrant (m, n)
  int l15 = lane & 15, quad = lane >> 4;

  f32x4 acc[4][4] = {};
  const size_t xbase = ((size_t)b * N_ + j0) * K;

  for (int kt = 0; kt < K; kt += 32) {
    __syncthreads();                        // LDS reuse guard
    #pragma unroll
    for (int q = 0; q < 2; ++q) {
      int s = q * 256 + t;                  // flat 16B slot 0..511
      int row = s >> 2, kq = s & 3;
      __builtin_amdgcn_global_load_lds(
          (gp_t)(Wb + (size_t)(m0 + row) * K + kt + kq * 8),
          (lp_t)(As + s * 8), 16, 0, 0);
      __builtin_amdgcn_global_load_lds(
          (gp_t)(Xb + xbase + (size_t)row * K + kt + kq * 8),
          (lp_t)(Bs + s * 8), 16, 0, 0);
    }
    __syncthreads();                        // drains vmcnt (gll) before reads

    bf16x8 af[4], bf[4];
    #pragma unroll
    for (int i = 0; i < 4; ++i)
      af[i] = *(const bf16x8*)(As + (64*wr + 16*i + l15) * 32 + quad * 8);
    #pragma unroll
    for (int i = 0; i < 4; ++i)
      bf[i] = *(const bf16x8*)(Bs + (64*wc + 16*i + l15) * 32 + quad * 8);
    #pragma unroll
    for (int im = 0; im < 4; ++im)
      #pragma unroll
      for (int in = 0; in < 4; ++in)
        acc[im][in] = __builtin_amdgcn_mfma_f32_16x16x32_bf16(af[im], bf[in], acc[im][in], 0, 0, 0);
  }

  // --- fused BN statistics: sum & sumsq per output channel m ---
  #pragma unroll
  for (int im = 0; im < 4; ++im) {
    #pragma unroll
    for (int r = 0; r < 4; ++r) {
      float sv = 0.f, qv = 0.f;
      #pragma unroll
      for (int in = 0; in < 4; ++in) { float v = acc[im][in][r]; sv += v; qv += v * v; }
      #pragma unroll
      for (int off = 1; off < 16; off <<= 1) {
        sv += __shfl_xor(sv, off, 64);
        qv += __shfl_xor(qv, off, 64);
      }
      if (l15 == 0) {
        int m = m0 + 64*wr + 16*im + 4*quad + r;
        atomicAdd(&stats[m], sv);
        atomicAdd(&stats[256 + m], qv);
      }
    }
  }

  // --- store ---
  if (OUTL == 0) {
    // h[b][n][m]: lane owns column n, 4 consecutive m per (im) -> float4 stores
    #pragma unroll
    for (int in = 0; in < 4; ++in) {
      size_t nrow = (size_t)b * N_ + j0 + 64*wc + 16*in + l15;
      float* p = outp + nrow * 256 + m0 + 64*wr + quad * 4;
      #pragma unroll
      for (int im = 0; im < 4; ++im)
        *(f32x4*)(p + 16 * im) = acc[im][in];
    }
  } else {
    // out[b][m][n]: 16-lane contiguous segments per row
    #pragma unroll
    for (int im = 0; im < 4; ++im)
      #pragma unroll
      for (int r = 0; r < 4; ++r) {
        int m = m0 + 64*wr + 16*im + 4*quad + r;
        size_t base = ((size_t)b * 256 + m) * N_ + j0 + 64*wc + l15;
        #pragma unroll
        for (int in = 0; in < 4; ++in)
          outp[base + 16 * in] = acc[im][in][r];
      }
  }
}

// ---------------------------------------------------------------------------
// 5) fold BN stats into per-channel scale/shift
// ---------------------------------------------------------------------------
__global__ void k_finalize_bn(const float* __restrict__ stats,
                              const float* __restrict__ gamma,
                              const float* __restrict__ beta,
                              float* __restrict__ bnp) {
  int c = threadIdx.x;
  const float inv = 1.0f / (float)(B_ * N_);
  float mean = stats[c] * inv;
  float var  = stats[256 + c] * inv - mean * mean;
  float rstd = 1.0f / sqrtf(var + 1e-5f);
  float sc = gamma[c] * rstd;
  bnp[c] = sc;
  bnp[256 + c] = beta[c] - mean * sc;
}

// ---------------------------------------------------------------------------
// 6) bn1 + relu + cast: h[b][n][256] fp32 -> Xb2[b][n][256] bf16
// ---------------------------------------------------------------------------
__global__ __launch_bounds__(256) void k_bn_relu_cast(const float* __restrict__ h,
                                                      const float* __restrict__ bnp,
                                                      unsigned short* __restrict__ Xb2) {
  size_t e = (size_t)blockIdx.x * 256 + threadIdx.x;   // float4 index
  float4 v = ((const float4*)h)[e];
  int c0 = (int)((e & 63) << 2);                       // 64 float4 per point-row
  float4 sc = *(const float4*)(bnp + c0);
  float4 sh = *(const float4*)(bnp + 256 + c0);
  ushort4 o;
  o.x = f2bf(fmaxf(fmaf(sc.x, v.x, sh.x), 0.0f));
  o.y = f2bf(fmaxf(fmaf(sc.y, v.y, sh.y), 0.0f));
  o.z = f2bf(fmaxf(fmaf(sc.z, v.z, sh.z), 0.0f));
  o.w = f2bf(fmaxf(fmaf(sc.w, v.w, sh.w), 0.0f));
  ((ushort4*)Xb2)[e] = o;
}

// ---------------------------------------------------------------------------
// 7) final BN + ReLU in place on d_out [B][H][N]
// ---------------------------------------------------------------------------
__global__ __launch_bounds__(256) void k_bn_relu(float* __restrict__ out,
                                                 const float* __restrict__ bnp) {
  size_t e = (size_t)blockIdx.x * 256 + threadIdx.x;
  float4 v = ((float4*)out)[e];
  int c = (int)((e >> 12) & 255);
  float sc = bnp[c], sh = bnp[256 + c];
  v.x = fmaxf(fmaf(sc, v.x, sh), 0.0f);
  v.y = fmaxf(fmaf(sc, v.y, sh), 0.0f);
  v.z = fmaxf(fmaf(sc, v.z, sh), 0.0f);
  v.w = fmaxf(fmaf(sc, v.w, sh), 0.0f);
  ((float4*)out)[e] = v;
}

// ---------------------------------------------------------------------------
extern "C" void kernel_launch(void* const* d_in, const int* in_sizes, int n_in,
                              void* d_out, int out_size, void* d_ws, size_t ws_size,
                              hipStream_t stream) {
  const float* unknown = (const float*)d_in[0];
  const float* known   = (const float*)d_in[1];
  const float* uf      = (const float*)d_in[2];
  const float* kf      = (const float*)d_in[3];
  const float* W1      = (const float*)d_in[4];
  const float* g1      = (const float*)d_in[5];
  const float* b1      = (const float*)d_in[6];
  const float* W2      = (const float*)d_in[7];
  const float* g2      = (const float*)d_in[8];
  const float* b2      = (const float*)d_in[9];
  float* out = (float*)d_out;

  // workspace layout (~67 MB):
  //   kfT   : B*M*C2 fp32                = 16.8 MB
  //   Xb1   : B*N*K1 bf16                = 48   MB  (GEMM1 B-operand)
  //           aliased: part (12.6 MB, dead before interp writes)
  //           aliased: Xb2 (32 MB, written after GEMM1 consumed Xb1)
  //   idx/wgt/Wb/stats/bnp               = ~2   MB
  // h (B*N*H fp32, 64 MB) lives in d_out until GEMM2 overwrites it.
  float* ws = (float*)d_ws;
  float*          kfT  = ws;                                          // 4194304 f
  unsigned short* Xb1  = (unsigned short*)(kfT + (size_t)B_*M_*C2_);  // 25165824 us
  double*         part = (double*)Xb1;                                // alias (early)
  unsigned short* Xb2  = Xb1;                                         // alias (late)
  int*   idx    = (int*)(Xb1 + (size_t)B_*N_*K1_);
  float* wgt    = (float*)(idx + (size_t)B_*N_*3);
  unsigned short* W1b = (unsigned short*)(wgt + (size_t)B_*N_*3);     // 98304 us
  unsigned short* W2b = W1b + H_*K1_;                                 // 65536 us
  float* stats1 = (float*)(W2b + H_*H_);
  float* stats2 = stats1 + 512;
  float* bnp1   = stats2 + 512;
  float* bnp2   = bnp1 + 512;
  float* h      = out;                                                // d_out scratch

  hipMemsetAsync(stats1, 0, 1024 * sizeof(float), stream);

  k_wcast<<<(H_*K1_ + 255)/256, 256, 0, stream>>>(W1, W1b, H_*K1_);
  k_wcast<<<(H_*H_  + 255)/256, 256, 0, stream>>>(W2, W2b, H_*H_);
  k_transpose<<<dim3(M_/32, C2_/32, B_), 256, 0, stream>>>(kf, kfT);
  k_three_nn_part<<<dim3(N_/256, B_, NC_), 256, 0, stream>>>(unknown, known, part);
  k_three_merge<<<dim3(N_/256, B_), 256, 0, stream>>>(part, idx, wgt);
  k_interp<<<dim3(N_/IP_, B_), 256, 0, stream>>>(kfT, idx, wgt, Xb1);
  k_uf_t<<<dim3(N_/32, C1_/32, B_), 256, 0, stream>>>(uf, Xb1);
  k_gemm_mfma<K1_, 0><<<dim3(N_/128, 2, B_), 256, 0, stream>>>(W1b, Xb1, h, stats1);
  k_finalize_bn<<<1, 256, 0, stream>>>(stats1, g1, b1, bnp1);
  k_bn_relu_cast<<<(int)((size_t)B_*N_*H_/4/256), 256, 0, stream>>>(h, bnp1, Xb2);
  k_gemm_mfma<H_, 1><<<dim3(N_/128, 2, B_), 256, 0, stream>>>(W2b, Xb2, out, stats2);
  k_finalize_bn<<<1, 256, 0, stream>>>(stats2, g2, b2, bnp2);
  k_bn_relu<<<(int)((size_t)B_*H_*N_/4/256), 256, 0, stream>>>(out, bnp2);
}

// Round 4
// 411.065 us; speedup vs baseline: 2.2960x; 1.3448x over previous
//
#include <hip/hip_runtime.h>
#include <math.h>

// Shapes (fixed by the problem)
#define B_   4
#define N_   16384
#define M_   4096
#define C1_  128
#define C2_  256
#define H_   256
#define K1_  384   // C1 + C2

#define NC_  8           // three_nn chunks over M
#define MC_  (M_ / NC_)  // 512 knowns per chunk
#define NB_  1024        // GEMM grid blocks (128 * 2 * 4) -> stats partials

typedef unsigned long long u64;
typedef __attribute__((ext_vector_type(8))) short bf16x8;   // 8 bf16 (4 VGPRs)
typedef __attribute__((ext_vector_type(4))) float f32x4;    // mfma acc

__device__ __forceinline__ unsigned short f2bf(float x) {
  unsigned u = __float_as_uint(x);
  return (unsigned short)((u + 0x7FFFu + ((u >> 16) & 1u)) >> 16);  // RNE
}

// ---------------------------------------------------------------------------
// 1) transpose known_feats [B, C2, M] -> kfT [B, M, C2] fp32 (for gathers)
// ---------------------------------------------------------------------------
__global__ __launch_bounds__(256) void k_transpose(const float* __restrict__ kf,
                                                   float* __restrict__ kfT) {
  __shared__ float tile[32][33];
  int b  = blockIdx.z;
  int i0 = blockIdx.x * 32;
  int c0 = blockIdx.y * 32;
  int tx  = threadIdx.x & 31;
  int tyv = threadIdx.x >> 5;
  const float* src = kf + ((size_t)b * C2_ + c0) * M_ + i0;
  #pragma unroll
  for (int r = 0; r < 32; r += 8)
    tile[tyv + r][tx] = src[(size_t)(tyv + r) * M_ + tx];
  __syncthreads();
  float* dst = kfT + ((size_t)b * M_ + i0) * C2_ + c0;
  #pragma unroll
  for (int r = 0; r < 32; r += 8)
    dst[(size_t)(tyv + r) * C2_ + tx] = tile[tx][tyv + r];
}

// ---------------------------------------------------------------------------
// 2a) three_nn partials (packed (d_bits<<32|idx) doubles, branchless top-3)
// ---------------------------------------------------------------------------
__global__ __launch_bounds__(256) void k_three_nn_part(const float* __restrict__ unknown,
                                                       const float* __restrict__ known,
                                                       double* __restrict__ part) {
  __shared__ float4 sk[MC_];
  int b    = blockIdx.y;
  int ch   = blockIdx.z;
  int base = ch * MC_;
  const float* kb = known + ((size_t)b * M_ + base) * 3;
  for (int i = threadIdx.x; i < MC_; i += 256) {
    float x = kb[3*i+0], y = kb[3*i+1], z = kb[3*i+2];
    sk[i] = make_float4(x, y, z, x*x + y*y + z*z);
  }
  __syncthreads();

  int j = blockIdx.x * 256 + threadIdx.x;
  const float* up = unknown + ((size_t)b * N_ + j) * 3;
  float ux = up[0], uy = up[1], uz = up[2];
  float u2 = ux*ux + uy*uy + uz*uz;

  const double INF = __builtin_inf();
  double s1 = INF, s2 = INF, s3 = INF;
  #pragma unroll 4
  for (int i = 0; i < MC_; ++i) {
    float4 k = sk[i];
    float dt = ux*k.x + uy*k.y + uz*k.z;
    float d  = (u2 + k.w) - 2.0f*dt;
    u64 pk = ((u64)__float_as_uint(d) << 32) | (unsigned)(base + i);
    double c = __longlong_as_double((long long)pk);
    double x3 = fmin(s3, c);
    s3 = fmax(s2, x3);
    double t  = fmin(s2, x3);
    s2 = fmax(s1, t);
    s1 = fmin(s1, t);
  }
  double* p = part + ((size_t)(ch * B_ + b) * 3) * N_ + j;
  p[0]            = s1;
  p[(size_t)N_]   = s2;
  p[2*(size_t)N_] = s3;
}

// ---------------------------------------------------------------------------
// 2b) merge partials -> idx + inverse-distance weights
// ---------------------------------------------------------------------------
__global__ __launch_bounds__(256) void k_three_merge(const double* __restrict__ part,
                                                     int* __restrict__ idx_o,
                                                     float* __restrict__ w_o) {
  int j = blockIdx.x * 256 + threadIdx.x;
  int b = blockIdx.y;
  const double* p0 = part + ((size_t)b * 3) * N_ + j;
  double s1 = p0[0], s2 = p0[(size_t)N_], s3 = p0[2*(size_t)N_];
  #pragma unroll
  for (int c = 1; c < NC_; ++c) {
    const double* pc = part + ((size_t)(c * B_ + b) * 3) * N_ + j;
    #pragma unroll
    for (int k = 0; k < 3; ++k) {
      double cv = pc[(size_t)k * N_];
      double x3 = fmin(s3, cv);
      s3 = fmax(s2, x3);
      double t  = fmin(s2, x3);
      s2 = fmax(s1, t);
      s1 = fmin(s1, t);
    }
  }
  u64 p1 = (u64)__double_as_longlong(s1);
  u64 p2 = (u64)__double_as_longlong(s2);
  u64 p3 = (u64)__double_as_longlong(s3);
  float d1 = __uint_as_float((unsigned)(p1 >> 32));
  float d2 = __uint_as_float((unsigned)(p2 >> 32));
  float d3 = __uint_as_float((unsigned)(p3 >> 32));
  float r1 = 1.0f / (d1 + 1e-8f);
  float r2 = 1.0f / (d2 + 1e-8f);
  float r3 = 1.0f / (d3 + 1e-8f);
  float s  = r1 + r2 + r3;
  size_t o = ((size_t)b * N_ + j) * 3;
  idx_o[o+0] = (int)(unsigned)p1;
  idx_o[o+1] = (int)(unsigned)p2;
  idx_o[o+2] = (int)(unsigned)p3;
  w_o[o+0] = r1 / s; w_o[o+1] = r2 / s; w_o[o+2] = r3 / s;
}

// ---------------------------------------------------------------------------
// 3a) three_interpolate -> Xb1[b][j][0:256] bf16 (point-major GEMM operand)
// ---------------------------------------------------------------------------
#define IP_ 32
__global__ __launch_bounds__(256) void k_interp(const float* __restrict__ kfT,
                                                const int* __restrict__ idx,
                                                const float* __restrict__ wgt,
                                                unsigned short* __restrict__ Xb1) {
  int b  = blockIdx.y;
  int j0 = blockIdx.x * IP_;
  const float* kb = kfT + (size_t)b * M_ * C2_;
  int c = threadIdx.x;
  for (int p = 0; p < IP_; ++p) {
    size_t pj = ((size_t)b * N_ + j0 + p) * 3;   // uniform -> scalar loads
    int   i0 = idx[pj+0], i1 = idx[pj+1], i2 = idx[pj+2];
    float w0 = wgt[pj+0], w1 = wgt[pj+1], w2 = wgt[pj+2];
    float v = w0 * kb[(size_t)i0 * C2_ + c]
            + w1 * kb[(size_t)i1 * C2_ + c]
            + w2 * kb[(size_t)i2 * C2_ + c];
    Xb1[((size_t)b * N_ + j0 + p) * K1_ + c] = f2bf(v);
  }
}

// ---------------------------------------------------------------------------
// 3b) transpose+cast unknown_feats [B,C1,N] fp32 -> Xb1[b][j][256+c] bf16
// ---------------------------------------------------------------------------
__global__ __launch_bounds__(256) void k_uf_t(const float* __restrict__ uf,
                                              unsigned short* __restrict__ Xb1) {
  __shared__ float tile[32][33];
  int b  = blockIdx.z;
  int j0 = blockIdx.x * 32;
  int c0 = blockIdx.y * 32;
  int tx = threadIdx.x & 31, ty = threadIdx.x >> 5;
  const float* src = uf + ((size_t)b * C1_ + c0) * N_ + j0;
  #pragma unroll
  for (int r = 0; r < 32; r += 8)
    tile[ty + r][tx] = src[(size_t)(ty + r) * N_ + tx];
  __syncthreads();
  unsigned short* dst = Xb1 + ((size_t)b * N_ + j0) * K1_ + C2_ + c0;
  #pragma unroll
  for (int r = 0; r < 32; r += 8)
    dst[(size_t)(ty + r) * K1_ + tx] = f2bf(tile[tx][ty + r]);
}

// ---------------------------------------------------------------------------
// 3c) cast weights to bf16 (row-major unchanged)
// ---------------------------------------------------------------------------
__global__ void k_wcast(const float* __restrict__ W, unsigned short* __restrict__ Wb, int n) {
  int i = blockIdx.x * 256 + threadIdx.x;
  if (i < n) Wb[i] = f2bf(W[i]);
}

// ---------------------------------------------------------------------------
// 4) bf16 MFMA GEMM, NO LDS staging, NO K-loop barriers.
//    MFMA fragments are loaded straight from global: per fragment one
//    global_load_dwordx4 (16 rows x 64B aligned segments, L2-resident).
//    128x128 tile, 4 waves (2x2 of 64x64), 16x mfma_16x16x32 per wave.
//    BN statistics: LDS-reduced per block, written as partials
//    stats_p[channel][block] (no global atomics, no contention).
//    OUTL 0: write h[b][n][m] fp32 (point-major, feeds bn_relu_cast)
//    OUTL 1: write out[b][m][n] fp32 (final layout)
// ---------------------------------------------------------------------------
template <int K, int OUTL>
__global__ __launch_bounds__(256) void k_gemm_mfma(const unsigned short* __restrict__ Wb,
                                                   const unsigned short* __restrict__ Xb,
                                                   float* __restrict__ outp,
                                                   float* __restrict__ stats_p) {
  __shared__ float sred[256];     // [0:128) sum, [128:256) sumsq for this m-tile
  int t = threadIdx.x;
  sred[t] = 0.0f;
  __syncthreads();

  int b  = blockIdx.z;
  int m0 = blockIdx.y * 128;
  int j0 = blockIdx.x * 128;
  int wid = t >> 6, lane = t & 63;
  int wr = wid >> 1, wc = wid & 1;          // wave quadrant (m, n)
  int l15 = lane & 15, quad = lane >> 4;

  // lane-resident base pointers: fragment row = lane&15, k-offset = quad*8
  const unsigned short* aptr = Wb + (size_t)(m0 + 64*wr + l15) * K + quad * 8;
  const unsigned short* bptr = Xb + ((size_t)b * N_ + j0 + 64*wc + l15) * K + quad * 8;

  f32x4 acc[4][4] = {};
  for (int kt = 0; kt < K; kt += 32) {
    bf16x8 af[4], bfr[4];
    #pragma unroll
    for (int i = 0; i < 4; ++i)
      af[i] = *(const bf16x8*)(aptr + (size_t)(16*i) * K + kt);
    #pragma unroll
    for (int i = 0; i < 4; ++i)
      bfr[i] = *(const bf16x8*)(bptr + (size_t)(16*i) * K + kt);
    #pragma unroll
    for (int im = 0; im < 4; ++im)
      #pragma unroll
      for (int in = 0; in < 4; ++in)
        acc[im][in] = __builtin_amdgcn_mfma_f32_16x16x32_bf16(af[im], bfr[in], acc[im][in], 0, 0, 0);
  }

  // --- BN statistics: shuffle-reduce over 16 n-lanes, combine in LDS ---
  #pragma unroll
  for (int im = 0; im < 4; ++im) {
    #pragma unroll
    for (int r = 0; r < 4; ++r) {
      float sv = 0.f, qv = 0.f;
      #pragma unroll
      for (int in = 0; in < 4; ++in) { float v = acc[im][in][r]; sv += v; qv += v * v; }
      #pragma unroll
      for (int off = 1; off < 16; off <<= 1) {
        sv += __shfl_xor(sv, off, 64);
        qv += __shfl_xor(qv, off, 64);
      }
      if (l15 == 0) {
        int ml = 64*wr + 16*im + 4*quad + r;   // 0..127 within tile
        atomicAdd(&sred[ml], sv);              // LDS atomic, 2-way at most
        atomicAdd(&sred[128 + ml], qv);
      }
    }
  }
  __syncthreads();
  if (t < 128) {
    int bid = (blockIdx.z * gridDim.y + blockIdx.y) * gridDim.x + blockIdx.x;
    stats_p[(size_t)(m0 + t) * NB_ + bid]       = sred[t];
    stats_p[(size_t)(256 + m0 + t) * NB_ + bid] = sred[128 + t];
  }

  // --- store ---
  if (OUTL == 0) {
    #pragma unroll
    for (int in = 0; in < 4; ++in) {
      size_t nrow = (size_t)b * N_ + j0 + 64*wc + 16*in + l15;
      float* p = outp + nrow * 256 + m0 + 64*wr + quad * 4;
      #pragma unroll
      for (int im = 0; im < 4; ++im)
        *(f32x4*)(p + 16 * im) = acc[im][in];
    }
  } else {
    #pragma unroll
    for (int im = 0; im < 4; ++im)
      #pragma unroll
      for (int r = 0; r < 4; ++r) {
        int m = m0 + 64*wr + 16*im + 4*quad + r;
        size_t base = ((size_t)b * 256 + m) * N_ + j0 + 64*wc + l15;
        #pragma unroll
        for (int in = 0; in < 4; ++in)
          outp[base + 16 * in] = acc[im][in][r];
      }
  }
}

// ---------------------------------------------------------------------------
// 5) reduce per-block stats partials -> bnp (scale/shift). One block per channel.
// ---------------------------------------------------------------------------
__global__ __launch_bounds__(256) void k_reduce_bn(const float* __restrict__ sp,
                                                   const float* __restrict__ gamma,
                                                   const float* __restrict__ beta,
                                                   float* __restrict__ bnp) {
  int c = blockIdx.x;        // 0..255
  int t = threadIdx.x;
  float s = 0.f, q = 0.f;
  for (int i = t; i < NB_; i += 256) {
    s += sp[(size_t)c * NB_ + i];
    q += sp[(size_t)(256 + c) * NB_ + i];
  }
  #pragma unroll
  for (int off = 32; off >= 1; off >>= 1) {
    s += __shfl_down(s, off, 64);
    q += __shfl_down(q, off, 64);
  }
  __shared__ float ss[4], qq[4];
  if ((t & 63) == 0) { ss[t >> 6] = s; qq[t >> 6] = q; }
  __syncthreads();
  if (t == 0) {
    s = ss[0] + ss[1] + ss[2] + ss[3];
    q = qq[0] + qq[1] + qq[2] + qq[3];
    const float inv = 1.0f / (float)(B_ * N_);
    float mean = s * inv;
    float var  = q * inv - mean * mean;
    float sc = gamma[c] / sqrtf(var + 1e-5f);
    bnp[c] = sc;
    bnp[256 + c] = beta[c] - mean * sc;
  }
}

// ---------------------------------------------------------------------------
// 6) bn1 + relu + cast: h[b][n][256] fp32 -> Xb2[b][n][256] bf16
// ---------------------------------------------------------------------------
__global__ __launch_bounds__(256) void k_bn_relu_cast(const float* __restrict__ h,
                                                      const float* __restrict__ bnp,
                                                      unsigned short* __restrict__ Xb2) {
  size_t e = (size_t)blockIdx.x * 256 + threadIdx.x;   // float4 index
  float4 v = ((const float4*)h)[e];
  int c0 = (int)((e & 63) << 2);                       // 64 float4 per point-row
  float4 sc = *(const float4*)(bnp + c0);
  float4 sh = *(const float4*)(bnp + 256 + c0);
  ushort4 o;
  o.x = f2bf(fmaxf(fmaf(sc.x, v.x, sh.x), 0.0f));
  o.y = f2bf(fmaxf(fmaf(sc.y, v.y, sh.y), 0.0f));
  o.z = f2bf(fmaxf(fmaf(sc.z, v.z, sh.z), 0.0f));
  o.w = f2bf(fmaxf(fmaf(sc.w, v.w, sh.w), 0.0f));
  ((ushort4*)Xb2)[e] = o;
}

// ---------------------------------------------------------------------------
// 7) final BN + ReLU in place on d_out [B][H][N]
// ---------------------------------------------------------------------------
__global__ __launch_bounds__(256) void k_bn_relu(float* __restrict__ out,
                                                 const float* __restrict__ bnp) {
  size_t e = (size_t)blockIdx.x * 256 + threadIdx.x;
  float4 v = ((float4*)out)[e];
  int c = (int)((e >> 12) & 255);
  float sc = bnp[c], sh = bnp[256 + c];
  v.x = fmaxf(fmaf(sc, v.x, sh), 0.0f);
  v.y = fmaxf(fmaf(sc, v.y, sh), 0.0f);
  v.z = fmaxf(fmaf(sc, v.z, sh), 0.0f);
  v.w = fmaxf(fmaf(sc, v.w, sh), 0.0f);
  ((float4*)out)[e] = v;
}

// ---------------------------------------------------------------------------
extern "C" void kernel_launch(void* const* d_in, const int* in_sizes, int n_in,
                              void* d_out, int out_size, void* d_ws, size_t ws_size,
                              hipStream_t stream) {
  const float* unknown = (const float*)d_in[0];
  const float* known   = (const float*)d_in[1];
  const float* uf      = (const float*)d_in[2];
  const float* kf      = (const float*)d_in[3];
  const float* W1      = (const float*)d_in[4];
  const float* g1      = (const float*)d_in[5];
  const float* b1      = (const float*)d_in[6];
  const float* W2      = (const float*)d_in[7];
  const float* g2      = (const float*)d_in[8];
  const float* b2      = (const float*)d_in[9];
  float* out = (float*)d_out;

  // workspace layout (~71 MB):
  //   kfT     : B*M*C2 fp32 = 16.8 MB
  //   Xb1     : B*N*K1 bf16 = 48 MB   (alias: part early, Xb2 late)
  //   idx/wgt : 1.6 MB
  //   W1b/W2b : 0.33 MB
  //   stats_p : 512*NB fp32 = 2 MB    (per-block BN partials, no memset needed)
  // h (B*N*H fp32, 64 MB) lives in d_out until GEMM2 overwrites it.
  float* ws = (float*)d_ws;
  float*          kfT  = ws;                                          // 4194304 f
  unsigned short* Xb1  = (unsigned short*)(kfT + (size_t)B_*M_*C2_);  // 25165824 us
  double*         part = (double*)Xb1;                                // alias (early)
  unsigned short* Xb2  = Xb1;                                         // alias (late)
  int*   idx    = (int*)(Xb1 + (size_t)B_*N_*K1_);
  float* wgt    = (float*)(idx + (size_t)B_*N_*3);
  unsigned short* W1b = (unsigned short*)(wgt + (size_t)B_*N_*3);     // 98304 us
  unsigned short* W2b = W1b + H_*K1_;                                 // 65536 us
  float* stats_p = (float*)(W2b + H_*H_);                             // 524288 f
  float* bnp1   = stats_p + 512 * NB_;
  float* bnp2   = bnp1 + 512;
  float* h      = out;                                                // d_out scratch

  k_wcast<<<(H_*K1_ + 255)/256, 256, 0, stream>>>(W1, W1b, H_*K1_);
  k_wcast<<<(H_*H_  + 255)/256, 256, 0, stream>>>(W2, W2b, H_*H_);
  k_transpose<<<dim3(M_/32, C2_/32, B_), 256, 0, stream>>>(kf, kfT);
  k_three_nn_part<<<dim3(N_/256, B_, NC_), 256, 0, stream>>>(unknown, known, part);
  k_three_merge<<<dim3(N_/256, B_), 256, 0, stream>>>(part, idx, wgt);
  k_interp<<<dim3(N_/IP_, B_), 256, 0, stream>>>(kfT, idx, wgt, Xb1);
  k_uf_t<<<dim3(N_/32, C1_/32, B_), 256, 0, stream>>>(uf, Xb1);
  k_gemm_mfma<K1_, 0><<<dim3(N_/128, 2, B_), 256, 0, stream>>>(W1b, Xb1, h, stats_p);
  k_reduce_bn<<<256, 256, 0, stream>>>(stats_p, g1, b1, bnp1);
  k_bn_relu_cast<<<(int)((size_t)B_*N_*H_/4/256), 256, 0, stream>>>(h, bnp1, Xb2);
  k_gemm_mfma<H_, 1><<<dim3(N_/128, 2, B_), 256, 0, stream>>>(W2b, Xb2, out, stats_p);
  k_reduce_bn<<<256, 256, 0, stream>>>(stats_p, g2, b2, bnp2);
  k_bn_relu<<<(int)((size_t)B_*H_*N_/4/256), 256, 0, stream>>>(out, bnp2);
}